// Round 17
// baseline (182.977 us; speedup 1.0000x reference)
//
#include <hip/hip_runtime.h>
#include <stdint.h>
#include <math.h>

typedef __attribute__((ext_vector_type(8))) __bf16 bf16x8;
typedef __attribute__((ext_vector_type(4))) float f32x4;

__device__ __forceinline__ unsigned short f2bf(float f) {
    unsigned u = __float_as_uint(f);
    u += 0x7FFF + ((u >> 16) & 1);
    return (unsigned short)(u >> 16);
}
__device__ __forceinline__ float bf2f(unsigned short u) {
    return __uint_as_float((unsigned)u << 16);
}

// ---- convert / transpose: z=0..3 X->Xb, z=4 Wq->WqT, z=5 Wk->WkT, z=6 Wv->Wvb ----
__global__ __launch_bounds__(256)
void convt_k(const float* __restrict__ X, const float* __restrict__ Wq,
             const float* __restrict__ Wk, const float* __restrict__ Wv,
             unsigned short* __restrict__ Xb, unsigned short* __restrict__ WqT,
             unsigned short* __restrict__ WkT, unsigned short* __restrict__ Wvb) {
    const int S = 2048, D = 1024;
    const int z = blockIdx.z;
    const int t = threadIdx.x;
    const float* src;
    unsigned short* dstP = nullptr;
    unsigned short* dstT = nullptr;
    int rows;
    if (z < 4)      { src = X + (size_t)z * S * D; dstP = Xb + (size_t)z * S * D; rows = S; }
    else if (z == 4){ src = Wq; dstT = WqT; rows = D; }
    else if (z == 5){ src = Wk; dstT = WkT; rows = D; }
    else            { src = Wv; dstP = Wvb; rows = D; }
    const int r0 = blockIdx.y * 64, c0 = blockIdx.x * 64;
    if (r0 >= rows) return;

    __shared__ float tile[64][65];
    const int tr = t >> 4;
    const int tc4 = t & 15;
#pragma unroll
    for (int p = 0; p < 4; ++p) {
        int r = p * 16 + tr;
        float4 v = *reinterpret_cast<const float4*>(&src[(size_t)(r0 + r) * 1024 + c0 + tc4 * 4]);
        if (dstP) {
            ushort4 o; o.x = f2bf(v.x); o.y = f2bf(v.y); o.z = f2bf(v.z); o.w = f2bf(v.w);
            *reinterpret_cast<ushort4*>(&dstP[(size_t)(r0 + r) * 1024 + c0 + tc4 * 4]) = o;
        }
        if (dstT) {
            tile[r][tc4 * 4 + 0] = v.x; tile[r][tc4 * 4 + 1] = v.y;
            tile[r][tc4 * 4 + 2] = v.z; tile[r][tc4 * 4 + 3] = v.w;
        }
    }
    if (!dstT) return;
    __syncthreads();
#pragma unroll
    for (int p = 0; p < 4; ++p) {
        int c = p * 16 + tr;
        ushort4 o;
        o.x = f2bf(tile[tc4 * 4 + 0][c]);
        o.y = f2bf(tile[tc4 * 4 + 1][c]);
        o.z = f2bf(tile[tc4 * 4 + 2][c]);
        o.w = f2bf(tile[tc4 * 4 + 3][c]);
        *reinterpret_cast<ushort4*>(&dstT[(size_t)(c0 + c) * 1024 + r0 + tc4 * 4]) = o;
    }
}

__global__ __launch_bounds__(256)
void reduce4_k(const float* __restrict__ p, unsigned short* __restrict__ o, int n4) {
    const int slab = 1024 * 1024 / 4;
    int i = blockIdx.x * blockDim.x + threadIdx.x;
    int stride = gridDim.x * blockDim.x;
    for (; i < n4; i += stride) {
        float4 a = reinterpret_cast<const float4*>(p)[i];
        float4 b = reinterpret_cast<const float4*>(p)[i + slab];
        float4 c = reinterpret_cast<const float4*>(p)[i + 2 * slab];
        float4 d = reinterpret_cast<const float4*>(p)[i + 3 * slab];
        ushort4 u;
        u.x = f2bf(a.x + b.x + c.x + d.x);
        u.y = f2bf(a.y + b.y + c.y + d.y);
        u.z = f2bf(a.z + b.z + c.z + d.z);
        u.w = f2bf(a.w + b.w + c.w + d.w);
        reinterpret_cast<ushort4*>(o)[i] = u;
    }
}

__device__ __forceinline__ void gload16(const unsigned short* g, unsigned short* l) {
    __builtin_amdgcn_global_load_lds(
        (const __attribute__((address_space(1))) unsigned int*)g,
        (__attribute__((address_space(3))) unsigned int*)l, 16, 0, 0);
}

// ===== 128x128 BK=64 tile core (proven r9-r16): counted vmcnt, XOR swizzle, dbuf =====
template <typename CT, bool ATOMIC>
__device__ __forceinline__ void core_tile(
    const unsigned short* __restrict__ A, const unsigned short* __restrict__ B,
    CT* __restrict__ C, int lda, int ldb, int ldc,
    int m0, int n0, int kst, int nk, float scale, bool first,
    unsigned short* AsB, unsigned short* BsB)
{
    const int t    = threadIdx.x;
    const int lane = t & 63;
    const int wid  = t >> 6;
    const int wm   = wid >> 1, wn = wid & 1;
    const int rsel = lane & 15;
    const int gsel = lane >> 4;
    const int srow = t >> 3;
    const int swz  = ((t & 7) ^ (srow & 7)) * 8;

    f32x4 acc[4][4];
#pragma unroll
    for (int m = 0; m < 4; ++m)
#pragma unroll
        for (int n = 0; n < 4; ++n) acc[m][n] = (f32x4){0.f, 0.f, 0.f, 0.f};

    const unsigned short* gpA[4];
    const unsigned short* gpB[4];
#pragma unroll
    for (int i = 0; i < 4; ++i) {
        gpA[i] = A + (long long)(m0 + srow + 32 * i) * lda + kst * 64 + swz;
        gpB[i] = B + (long long)(n0 + srow + 32 * i) * ldb + kst * 64 + swz;
    }

    auto stage = [&](int buf) {
#pragma unroll
        for (int i = 0; i < 4; ++i)
            gload16(gpA[i], &AsB[buf * 8192 + i * 2048 + t * 8]);
#pragma unroll
        for (int i = 0; i < 4; ++i)
            gload16(gpB[i], &BsB[buf * 8192 + i * 2048 + t * 8]);
#pragma unroll
        for (int i = 0; i < 4; ++i) { gpA[i] += 64; gpB[i] += 64; }
    };

    if (!first) {
        __builtin_amdgcn_s_barrier();
        __builtin_amdgcn_sched_barrier(0);
    }
    stage(0);

    for (int kt = 0; kt < nk; ++kt) {
        const int c = kt & 1;
        __builtin_amdgcn_s_barrier();
        __builtin_amdgcn_sched_barrier(0);
        if (kt + 1 < nk) {
            stage(c ^ 1);
            asm volatile("s_waitcnt vmcnt(8)" ::: "memory");
        } else {
            asm volatile("s_waitcnt vmcnt(0)" ::: "memory");
        }
        __builtin_amdgcn_s_barrier();
        __builtin_amdgcn_sched_barrier(0);

        bf16x8 aF[4][2], bF[4][2];
#pragma unroll
        for (int m = 0; m < 4; ++m)
#pragma unroll
            for (int ks = 0; ks < 2; ++ks) {
                int r  = wm * 64 + m * 16 + rsel;
                int cc = ks * 4 + gsel;
                aF[m][ks] = *reinterpret_cast<const bf16x8*>(
                    &AsB[c * 8192 + r * 64 + ((cc ^ (r & 7)) * 8)]);
            }
#pragma unroll
        for (int n = 0; n < 4; ++n)
#pragma unroll
            for (int ks = 0; ks < 2; ++ks) {
                int rb = wn * 64 + n * 16 + rsel;
                int cc = ks * 4 + gsel;
                bF[n][ks] = *reinterpret_cast<const bf16x8*>(
                    &BsB[c * 8192 + rb * 64 + ((cc ^ (rb & 7)) * 8)]);
            }

        __builtin_amdgcn_s_setprio(1);
#pragma unroll
        for (int m = 0; m < 4; ++m)
#pragma unroll
            for (int n = 0; n < 4; ++n)
#pragma unroll
                for (int ks = 0; ks < 2; ++ks)
                    acc[m][n] = __builtin_amdgcn_mfma_f32_16x16x32_bf16(
                        aF[m][ks], bF[n][ks], acc[m][n], 0, 0, 0);
        __builtin_amdgcn_s_setprio(0);
    }

    const int rowl = gsel * 4;
#pragma unroll
    for (int m = 0; m < 4; ++m)
#pragma unroll
        for (int n = 0; n < 4; ++n)
#pragma unroll
            for (int i = 0; i < 4; ++i) {
                int r  = m0 + wm * 64 + m * 16 + rowl + i;
                int cI = n0 + wn * 64 + n * 16 + rsel;
                float v = acc[m][n][i] * scale;
                if constexpr (sizeof(CT) == 2)
                    ((unsigned short*)C)[(long long)r * ldc + cI] = f2bf(v);
                else if constexpr (ATOMIC)
                    unsafeAtomicAdd((float*)&C[(long long)r * ldc + cI], v);
                else
                    ((float*)C)[(long long)r * ldc + cI] = v;
            }
}

__device__ __forceinline__ void tri_decode(int w, int& br, int& bc) {
    int rr = (int)((sqrtf(8.0f * (float)w + 1.0f) - 1.0f) * 0.5f);
    while ((rr + 1) * (rr + 2) / 2 <= w) ++rr;
    while (rr * (rr + 1) / 2 > w) --rr;
    br = rr; bc = w - rr * (rr + 1) / 2;
}

// dense MODE0 GEMM (M1 split-K): XCD-remapped uniform grid
template <typename CT>
__global__ __launch_bounds__(256, 2)
void gemm0(const unsigned short* __restrict__ A, const unsigned short* __restrict__ B,
           CT* __restrict__ C, int lda, int ldb, int ldc, int K,
           long long sA, long long sB, long long sC, float scale)
{
    __shared__ unsigned short As[2 * 8192];
    __shared__ unsigned short Bs[2 * 8192];
    const int nbx = gridDim.x;
    const int nwg = nbx * gridDim.y;
    const int orig = blockIdx.y * nbx + blockIdx.x;
    const int q8 = nwg >> 3, r8 = nwg & 7;
    const int xcd = orig & 7, idx = orig >> 3;
    const int work = (xcd < r8 ? xcd * (q8 + 1) : r8 * (q8 + 1) + (xcd - r8) * q8) + idx;
    core_tile<CT, false>(A + (long long)blockIdx.z * sA, B + (long long)blockIdx.z * sB,
                         C + (long long)blockIdx.z * sC, lda, ldb, ldc,
                         (work / nbx) * 128, (work % nbx) * 128, 0, K >> 6, scale, true,
                         As, Bs);
}

// merged XM (512 jobs) + Vt (512 jobs): 1024 uniform 16-step jobs
__global__ __launch_bounds__(256, 2)
void gemm_xmvt(const unsigned short* __restrict__ Xb, const unsigned short* __restrict__ MTb,
               unsigned short* __restrict__ XMb, const unsigned short* __restrict__ Wv,
               unsigned short* __restrict__ Vt)
{
    const int S = 2048, D = 1024;
    const long long SD = (long long)S * D, DS = (long long)D * S;
    __shared__ unsigned short As[2 * 8192];
    __shared__ unsigned short Bs[2 * 8192];
    const int orig = blockIdx.x;
    const int work = (orig & 7) * 128 + (orig >> 3);     // nwg=1024, bijective
    if (work < 512) {                                    // XM = Xb * M
        int rw = work >> 3, c = work & 7;
        core_tile<unsigned short, false>(Xb, MTb, XMb, D, D, D,
            rw * 128, c * 128, 0, 16, 1.0f, true, As, Bs);
    } else {                                             // Vt[b] = Wv @ Xb[b]^T
        int v = work - 512;
        int b = v >> 7, u = v & 127;
        int r = u >> 4, c = u & 15;
        core_tile<unsigned short, false>(Wv, Xb + b * SD, Vt + b * DS, D, D, S,
            r * 128, c * 128, 0, 16, 1.0f, true, As, Bs);
    }
}

// scores: 544 FM=4 tri-tiles x 2 K-halves = 1088 uniform 8-step jobs.
// half 0 -> ScA (k 0..511), half 1 -> ScB (k 512..1023); softmax sums.
__global__ __launch_bounds__(256, 2)
void gemm_sc(const unsigned short* __restrict__ XM, const unsigned short* __restrict__ Xb,
             unsigned short* __restrict__ ScA, unsigned short* __restrict__ ScB)
{
    const int S = 2048, D = 1024;
    const long long SD = (long long)S * D, SS = (long long)S * S;
    __shared__ unsigned short As[2 * 8192];
    __shared__ unsigned short Bs[2 * 8192];
    const int orig = blockIdx.x;                         // 1088 = 8*136
    const int work = (orig & 7) * 136 + (orig >> 3);
    const int tile = work >> 1, half = work & 1;         // adjacent works share a tile
    const int b = tile / 136, tt = tile % 136;
    int br, bc;
    tri_decode(tt, br, bc);
    unsigned short* dst = half ? ScB : ScA;
    core_tile<unsigned short, false>(XM + b * SD, Xb + b * SD, dst + b * SS,
        D, D, S, br * 128, bc * 128, half * 8, 8, 0.03125f, true, As, Bs);
}

// PV: FM=4 tiles chopped into <=8-step K-chunks -> 1280 jobs (40 per (b,c)),
// longest-first within each XCD chunk; r0-3 single-chunk direct, r>=4 atomic
// (out rows >=512 zero-initialized by softmax).
__global__ __launch_bounds__(256, 2)
void gemm_pv(const unsigned short* __restrict__ P, const unsigned short* __restrict__ Vt,
             float* __restrict__ out)
{
    const int S = 2048, D = 1024;
    const long long SS = (long long)S * S, DS = (long long)D * S, SD = (long long)S * D;
    __shared__ unsigned short As[2 * 8192];
    __shared__ unsigned short Bs[2 * 8192];
    const int orig = blockIdx.x;                         // 1280 = 8*160
    const int work = (orig & 7) * 160 + (orig >> 3);
    const int g = work / 40;                             // (b,c) group
    const int u = 39 - (work % 40);                      // longest-first
    const int b = g >> 3, c = g & 7;

    int r, i, n;
    if (u < 4)       { r = u;                 i = 0;           n = 1; }
    else if (u < 12) { r = 4  + ((u - 4) >> 1);  i = (u - 4) & 1;  n = 2; }
    else if (u < 24) { r = 8  + (u - 12) / 3;    i = (u - 12) % 3; n = 3; }
    else             { r = 12 + ((u - 24) >> 2); i = (u - 24) & 3; n = 4; }
    const int steps = 2 * (r + 1);
    const int kst = i * steps / n;
    const int nk  = (i + 1) * steps / n - kst;

    if (n == 1)
        core_tile<float, false>(P + b * SS, Vt + b * DS, out + b * SD, S, S, D,
            r * 128, c * 128, kst, nk, 1.0f, true, As, Bs);
    else
        core_tile<float, true>(P + b * SS, Vt + b * DS, out + b * SD, S, S, D,
            r * 128, c * 128, kst, nk, 1.0f, true, As, Bs);
}

// ---- causal row softmax: sums bf16 score halves, writes bf16 P,
// ---- and zero-inits out rows >= 512 (PV atomic targets) ----
__device__ __forceinline__ float waveMax(float v) {
#pragma unroll
    for (int o = 32; o > 0; o >>= 1) v = fmaxf(v, __shfl_xor(v, o, 64));
    return v;
}
__device__ __forceinline__ float waveSum(float v) {
#pragma unroll
    for (int o = 32; o > 0; o >>= 1) v += __shfl_xor(v, o, 64);
    return v;
}

__global__ __launch_bounds__(256)
void softmax_causal(const unsigned short* __restrict__ SA, const unsigned short* __restrict__ SB,
                    unsigned short* __restrict__ P, float* __restrict__ out, int Slen) {
    __shared__ float e[2048];
    __shared__ float red[4];
    long long row = blockIdx.x;
    int q = (int)(row % Slen);
    const unsigned short* sa = SA + row * (long long)Slen;
    const unsigned short* sb = SB + row * (long long)Slen;
    unsigned short* prow = P + row * (long long)Slen;
    int len = q + 1;
    int t = threadIdx.x;

    // zero-init this row of out if it is an atomic PV target (q >= 512)
    if (q >= 512) {
        float4 zz = (float4){0.f, 0.f, 0.f, 0.f};
        reinterpret_cast<float4*>(out + row * 1024)[t] = zz;   // 256 thr x 16B = 4KB row
    }

    int n8 = len >> 3;
    float mx = -3.0e38f;
    for (int i = t; i < n8; i += 256) {
        uint4 va = reinterpret_cast<const uint4*>(sa)[i];
        uint4 vb = reinterpret_cast<const uint4*>(sb)[i];
        float f0 = __uint_as_float(va.x << 16) + __uint_as_float(vb.x << 16);
        float f1 = __uint_as_float(va.x & 0xffff0000u) + __uint_as_float(vb.x & 0xffff0000u);
        float f2 = __uint_as_float(va.y << 16) + __uint_as_float(vb.y << 16);
        float f3 = __uint_as_float(va.y & 0xffff0000u) + __uint_as_float(vb.y & 0xffff0000u);
        float f4 = __uint_as_float(va.z << 16) + __uint_as_float(vb.z << 16);
        float f5 = __uint_as_float(va.z & 0xffff0000u) + __uint_as_float(vb.z & 0xffff0000u);
        float f6 = __uint_as_float(va.w << 16) + __uint_as_float(vb.w << 16);
        float f7 = __uint_as_float(va.w & 0xffff0000u) + __uint_as_float(vb.w & 0xffff0000u);
        e[8 * i + 0] = f0; e[8 * i + 1] = f1; e[8 * i + 2] = f2; e[8 * i + 3] = f3;
        e[8 * i + 4] = f4; e[8 * i + 5] = f5; e[8 * i + 6] = f6; e[8 * i + 7] = f7;
        mx = fmaxf(mx, fmaxf(fmaxf(fmaxf(f0, f1), fmaxf(f2, f3)),
                             fmaxf(fmaxf(f4, f5), fmaxf(f6, f7))));
    }
    if (t < (len & 7)) {
        float v = bf2f(sa[n8 * 8 + t]) + bf2f(sb[n8 * 8 + t]);
        e[n8 * 8 + t] = v;
        mx = fmaxf(mx, v);
    }
    mx = waveMax(mx);
    if ((t & 63) == 0) red[t >> 6] = mx;
    __syncthreads();
    mx = fmaxf(fmaxf(red[0], red[1]), fmaxf(red[2], red[3]));

    float sum = 0.f;
    for (int k = t; k < len; k += 256) {
        float v = __expf(e[k] - mx);
        e[k] = v;
        sum += v;
    }
    sum = waveSum(sum);
    __syncthreads();
    if ((t & 63) == 0) red[t >> 6] = sum;
    __syncthreads();
    sum = red[0] + red[1] + red[2] + red[3];
    float inv = 1.0f / sum;

    int wlim = ((q >> 7) + 1) << 7;             // PV (128-row tiles) reads k < roundup(len,128)
    __syncthreads();
    for (int i = t; i < (wlim >> 2); i += 256) {
        int k = 4 * i;
        ushort4 o;
        o.x = (k + 0 < len) ? f2bf(e[k + 0] * inv) : (unsigned short)0;
        o.y = (k + 1 < len) ? f2bf(e[k + 1] * inv) : (unsigned short)0;
        o.z = (k + 2 < len) ? f2bf(e[k + 2] * inv) : (unsigned short)0;
        o.w = (k + 3 < len) ? f2bf(e[k + 3] * inv) : (unsigned short)0;
        reinterpret_cast<ushort4*>(prow)[i] = o;
    }
}

extern "C" void kernel_launch(void* const* d_in, const int* in_sizes, int n_in,
                              void* d_out, int out_size, void* d_ws, size_t ws_size,
                              hipStream_t stream) {
    const int B = 4, S = 2048, D = 1024;
    const float* X  = (const float*)d_in[0];
    const float* Wq = (const float*)d_in[1];
    const float* Wk = (const float*)d_in[2];
    const float* Wv = (const float*)d_in[3];
    float* out = (float*)d_out;

    char* ws = (char*)d_ws;
    unsigned short* Xb    = (unsigned short*)ws; ws += (size_t)B * S * D * 2;
    unsigned short* WqT   = (unsigned short*)ws; ws += (size_t)D * D * 2;
    unsigned short* WkT   = (unsigned short*)ws; ws += (size_t)D * D * 2;
    unsigned short* Wvb   = (unsigned short*)ws; ws += (size_t)D * D * 2;
    unsigned short* MTb   = (unsigned short*)ws; ws += (size_t)D * D * 2;
    unsigned short* XMb   = (unsigned short*)ws; ws += (size_t)B * S * D * 2;
    unsigned short* Vt    = (unsigned short*)ws; ws += (size_t)B * D * S * 2;
    unsigned short* ScA   = (unsigned short*)ws; ws += (size_t)B * S * S * 2;
    unsigned short* ScB   = (unsigned short*)ws; ws += (size_t)B * S * S * 2;
    unsigned short* P     = (unsigned short*)ws; ws += (size_t)B * S * S * 2;
    float*          Mpart = (float*)ws;          ws += (size_t)4 * D * D * 4;

    // 1) converts + W transposes
    convt_k<<<dim3(16, 32, 7), 256, 0, stream>>>(X, Wq, Wk, Wv, Xb, WqT, WkT, Wvb);

    dim3 blk(256);
    // 2) MT = Wk^T * Wq, split-K (z = k-chunk of 256)
    gemm0<float><<<dim3(8, 8, 4), blk, 0, stream>>>(
        WkT, WqT, Mpart, D, D, D, 256, 256, 256, (long long)D * D, 1.0f);
    reduce4_k<<<1024, 256, 0, stream>>>(Mpart, MTb, D * D / 4);

    // 3) XM = Xb*M  +  Vt = Wv @ X^T : 1024 uniform 16-step jobs
    gemm_xmvt<<<dim3(1024, 1, 1), blk, 0, stream>>>(Xb, MTb, XMb, Wvb, Vt);

    // 4) scores (tri, /32, bf16, K-halved): 1088 uniform 8-step jobs
    gemm_sc<<<dim3(1088, 1, 1), blk, 0, stream>>>(XMb, Xb, ScA, ScB);

    // 5) causal softmax (sums halves) -> P ; zero-inits atomic out rows
    softmax_causal<<<B * S, 256, 0, stream>>>(ScA, ScB, P, out, S);

    // 6) out = P @ Vt^T : 1280 <=8-step jobs, longest-first, r>=4 atomic
    gemm_pv<<<dim3(1280, 1, 1), blk, 0, stream>>>(P, Vt, out);
}

// Round 18
// 144.470 us; speedup vs baseline: 1.2665x; 1.2665x over previous
//
#include <hip/hip_runtime.h>
#include <stdint.h>
#include <math.h>

typedef __attribute__((ext_vector_type(8))) __bf16 bf16x8;
typedef __attribute__((ext_vector_type(4))) float f32x4;

__device__ __forceinline__ unsigned short f2bf(float f) {
    unsigned u = __float_as_uint(f);
    u += 0x7FFF + ((u >> 16) & 1);
    return (unsigned short)(u >> 16);
}
__device__ __forceinline__ float bf2f(unsigned short u) {
    return __uint_as_float((unsigned)u << 16);
}

// ---- convert / transpose: z=0..3 X->Xb, z=4 Wq->WqT, z=5 Wk->WkT, z=6 Wv->Wvb ----
__global__ __launch_bounds__(256)
void convt_k(const float* __restrict__ X, const float* __restrict__ Wq,
             const float* __restrict__ Wk, const float* __restrict__ Wv,
             unsigned short* __restrict__ Xb, unsigned short* __restrict__ WqT,
             unsigned short* __restrict__ WkT, unsigned short* __restrict__ Wvb) {
    const int S = 2048, D = 1024;
    const int z = blockIdx.z;
    const int t = threadIdx.x;
    const float* src;
    unsigned short* dstP = nullptr;
    unsigned short* dstT = nullptr;
    int rows;
    if (z < 4)      { src = X + (size_t)z * S * D; dstP = Xb + (size_t)z * S * D; rows = S; }
    else if (z == 4){ src = Wq; dstT = WqT; rows = D; }
    else if (z == 5){ src = Wk; dstT = WkT; rows = D; }
    else            { src = Wv; dstP = Wvb; rows = D; }
    const int r0 = blockIdx.y * 64, c0 = blockIdx.x * 64;
    if (r0 >= rows) return;

    __shared__ float tile[64][65];
    const int tr = t >> 4;
    const int tc4 = t & 15;
#pragma unroll
    for (int p = 0; p < 4; ++p) {
        int r = p * 16 + tr;
        float4 v = *reinterpret_cast<const float4*>(&src[(size_t)(r0 + r) * 1024 + c0 + tc4 * 4]);
        if (dstP) {
            ushort4 o; o.x = f2bf(v.x); o.y = f2bf(v.y); o.z = f2bf(v.z); o.w = f2bf(v.w);
            *reinterpret_cast<ushort4*>(&dstP[(size_t)(r0 + r) * 1024 + c0 + tc4 * 4]) = o;
        }
        if (dstT) {
            tile[r][tc4 * 4 + 0] = v.x; tile[r][tc4 * 4 + 1] = v.y;
            tile[r][tc4 * 4 + 2] = v.z; tile[r][tc4 * 4 + 3] = v.w;
        }
    }
    if (!dstT) return;
    __syncthreads();
#pragma unroll
    for (int p = 0; p < 4; ++p) {
        int c = p * 16 + tr;
        ushort4 o;
        o.x = f2bf(tile[tc4 * 4 + 0][c]);
        o.y = f2bf(tile[tc4 * 4 + 1][c]);
        o.z = f2bf(tile[tc4 * 4 + 2][c]);
        o.w = f2bf(tile[tc4 * 4 + 3][c]);
        *reinterpret_cast<ushort4*>(&dstT[(size_t)(c0 + c) * 1024 + r0 + tc4 * 4]) = o;
    }
}

__global__ __launch_bounds__(256)
void reduce4_k(const float* __restrict__ p, unsigned short* __restrict__ o, int n4) {
    const int slab = 1024 * 1024 / 4;
    int i = blockIdx.x * blockDim.x + threadIdx.x;
    int stride = gridDim.x * blockDim.x;
    for (; i < n4; i += stride) {
        float4 a = reinterpret_cast<const float4*>(p)[i];
        float4 b = reinterpret_cast<const float4*>(p)[i + slab];
        float4 c = reinterpret_cast<const float4*>(p)[i + 2 * slab];
        float4 d = reinterpret_cast<const float4*>(p)[i + 3 * slab];
        ushort4 u;
        u.x = f2bf(a.x + b.x + c.x + d.x);
        u.y = f2bf(a.y + b.y + c.y + d.y);
        u.z = f2bf(a.z + b.z + c.z + d.z);
        u.w = f2bf(a.w + b.w + c.w + d.w);
        reinterpret_cast<ushort4*>(o)[i] = u;
    }
}

__device__ __forceinline__ void gload16(const unsigned short* g, unsigned short* l) {
    __builtin_amdgcn_global_load_lds(
        (const __attribute__((address_space(1))) unsigned int*)g,
        (__attribute__((address_space(3))) unsigned int*)l, 16, 0, 0);
}

// ===== FMx32-row x 128-col BK=64 tile core (FM=4: proven r9-r15; FM=2: 64-row) =====
// counted vmcnt(FM+4), XOR swizzle, double-buffered, 4 waves (2x2).
template <int FM, typename CT>
__device__ __forceinline__ void core_tile(
    const unsigned short* __restrict__ A, const unsigned short* __restrict__ B,
    CT* __restrict__ C, int lda, int ldb, int ldc,
    int m0, int n0, int kst, int nk, float scale, bool first,
    unsigned short* AsB, unsigned short* BsB)
{
    constexpr int FN = 4;
    const int t    = threadIdx.x;
    const int lane = t & 63;
    const int wid  = t >> 6;
    const int wm   = wid >> 1, wn = wid & 1;
    const int rsel = lane & 15;
    const int gsel = lane >> 4;
    const int srow = t >> 3;
    const int swz  = ((t & 7) ^ (srow & 7)) * 8;

    f32x4 acc[FM][FN];
#pragma unroll
    for (int m = 0; m < FM; ++m)
#pragma unroll
        for (int n = 0; n < FN; ++n) acc[m][n] = (f32x4){0.f, 0.f, 0.f, 0.f};

    const unsigned short* gpA[FM];
    const unsigned short* gpB[4];
#pragma unroll
    for (int i = 0; i < FM; ++i)
        gpA[i] = A + (long long)(m0 + srow + 32 * i) * lda + kst * 64 + swz;
#pragma unroll
    for (int i = 0; i < 4; ++i)
        gpB[i] = B + (long long)(n0 + srow + 32 * i) * ldb + kst * 64 + swz;

    auto stage = [&](int buf) {
#pragma unroll
        for (int i = 0; i < FM; ++i)
            gload16(gpA[i], &AsB[buf * (FM * 2048) + i * 2048 + t * 8]);
#pragma unroll
        for (int i = 0; i < 4; ++i)
            gload16(gpB[i], &BsB[buf * 8192 + i * 2048 + t * 8]);
#pragma unroll
        for (int i = 0; i < FM; ++i) gpA[i] += 64;
#pragma unroll
        for (int i = 0; i < 4; ++i) gpB[i] += 64;
    };

    if (!first) {
        __builtin_amdgcn_s_barrier();
        __builtin_amdgcn_sched_barrier(0);
    }
    stage(0);

    for (int kt = 0; kt < nk; ++kt) {
        const int c = kt & 1;
        __builtin_amdgcn_s_barrier();
        __builtin_amdgcn_sched_barrier(0);
        if (kt + 1 < nk) {
            stage(c ^ 1);
            if constexpr (FM == 4) asm volatile("s_waitcnt vmcnt(8)" ::: "memory");
            else                   asm volatile("s_waitcnt vmcnt(6)" ::: "memory");
        } else {
            asm volatile("s_waitcnt vmcnt(0)" ::: "memory");
        }
        __builtin_amdgcn_s_barrier();
        __builtin_amdgcn_sched_barrier(0);

        bf16x8 aF[FM][2], bF[FN][2];
#pragma unroll
        for (int m = 0; m < FM; ++m)
#pragma unroll
            for (int ks = 0; ks < 2; ++ks) {
                int r  = wm * (FM * 16) + m * 16 + rsel;
                int cc = ks * 4 + gsel;
                aF[m][ks] = *reinterpret_cast<const bf16x8*>(
                    &AsB[c * (FM * 2048) + r * 64 + ((cc ^ (r & 7)) * 8)]);
            }
#pragma unroll
        for (int n = 0; n < FN; ++n)
#pragma unroll
            for (int ks = 0; ks < 2; ++ks) {
                int rb = wn * 64 + n * 16 + rsel;
                int cc = ks * 4 + gsel;
                bF[n][ks] = *reinterpret_cast<const bf16x8*>(
                    &BsB[c * 8192 + rb * 64 + ((cc ^ (rb & 7)) * 8)]);
            }

        __builtin_amdgcn_s_setprio(1);
#pragma unroll
        for (int m = 0; m < FM; ++m)
#pragma unroll
            for (int n = 0; n < FN; ++n)
#pragma unroll
                for (int ks = 0; ks < 2; ++ks)
                    acc[m][n] = __builtin_amdgcn_mfma_f32_16x16x32_bf16(
                        aF[m][ks], bF[n][ks], acc[m][n], 0, 0, 0);
        __builtin_amdgcn_s_setprio(0);
    }

    const int rowl = gsel * 4;
#pragma unroll
    for (int m = 0; m < FM; ++m)
#pragma unroll
        for (int n = 0; n < FN; ++n)
#pragma unroll
            for (int i = 0; i < 4; ++i) {
                int r  = m0 + wm * (FM * 16) + m * 16 + rowl + i;
                int cI = n0 + wn * 64 + n * 16 + rsel;
                float v = acc[m][n][i] * scale;
                if constexpr (sizeof(CT) == 2)
                    ((unsigned short*)C)[(long long)r * ldc + cI] = f2bf(v);
                else
                    ((float*)C)[(long long)r * ldc + cI] = v;
            }
}

// dense MODE0 GEMM (M1 split-K): XCD-remapped uniform grid
template <typename CT>
__global__ __launch_bounds__(256, 2)
void gemm0(const unsigned short* __restrict__ A, const unsigned short* __restrict__ B,
           CT* __restrict__ C, int lda, int ldb, int ldc, int K,
           long long sA, long long sB, long long sC, float scale)
{
    __shared__ unsigned short As[2 * 8192];
    __shared__ unsigned short Bs[2 * 8192];
    const int nbx = gridDim.x;
    const int nwg = nbx * gridDim.y;
    const int orig = blockIdx.y * nbx + blockIdx.x;
    const int q8 = nwg >> 3, r8 = nwg & 7;
    const int xcd = orig & 7, idx = orig >> 3;
    const int work = (xcd < r8 ? xcd * (q8 + 1) : r8 * (q8 + 1) + (xcd - r8) * q8) + idx;
    core_tile<4, CT>(A + (long long)blockIdx.z * sA, B + (long long)blockIdx.z * sB,
                     C + (long long)blockIdx.z * sC, lda, ldb, ldc,
                     (work / nbx) * 128, (work % nbx) * 128, 0, K >> 6, scale, true,
                     As, Bs);
}

// merged XM (512 jobs) + Vt (512 jobs): 1024 uniform 16-step jobs, FM=4
__global__ __launch_bounds__(256, 2)
void gemm_xmvt(const unsigned short* __restrict__ Xb, const unsigned short* __restrict__ MTb,
               unsigned short* __restrict__ XMb, const unsigned short* __restrict__ Wv,
               unsigned short* __restrict__ Vt)
{
    const int S = 2048, D = 1024;
    const long long SD = (long long)S * D, DS = (long long)D * S;
    __shared__ unsigned short As[2 * 8192];
    __shared__ unsigned short Bs[2 * 8192];
    const int orig = blockIdx.x;
    const int work = (orig & 7) * 128 + (orig >> 3);     // nwg=1024, bijective
    if (work < 512) {                                    // XM = Xb * M
        int rw = work >> 3, c = work & 7;
        core_tile<4, unsigned short>(Xb, MTb, XMb, D, D, D,
            rw * 128, c * 128, 0, 16, 1.0f, true, As, Bs);
    } else {                                             // Vt[b] = Wv @ Xb[b]^T
        int v = work - 512;
        int b = v >> 7, u = v & 127;
        int r = u >> 4, c = u & 15;
        core_tile<4, unsigned short>(Wv, Xb + b * SD, Vt + b * DS, D, D, S,
            r * 128, c * 128, 0, 16, 1.0f, true, As, Bs);
    }
}

// scores = (XM * Xb^T)/32 : 64-row tri tiles, 272/batch = 1088 uniform 16-step jobs
__global__ __launch_bounds__(256, 2)
void gemm_sc(const unsigned short* __restrict__ XM, const unsigned short* __restrict__ Xb,
             unsigned short* __restrict__ Sc)
{
    const int S = 2048, D = 1024;
    const long long SD = (long long)S * D, SS = (long long)S * S;
    __shared__ unsigned short As[2 * 4096];
    __shared__ unsigned short Bs[2 * 8192];
    const int orig = blockIdx.x;                         // 1088 = 8*136
    const int work = (orig & 7) * 136 + (orig >> 3);
    const int b = work / 272, j = work % 272;
    // decode: pair a (rows 2a, 2a+1) each has a+1 cols; cum before pair a = a(a+1)
    int a = (int)((sqrtf(4.0f * (float)j + 1.0f) - 1.0f) * 0.5f);
    while ((a + 1) * (a + 2) <= j) ++a;
    while (a * (a + 1) > j) --a;
    const int off = j - a * (a + 1);                     // 0 .. 2a+1
    const int r = 2 * a + (off > a ? 1 : 0);
    const int c = (off > a) ? (off - a - 1) : off;
    core_tile<2, unsigned short>(XM + b * SD, Xb + b * SD, Sc + b * SS,
        D, D, S, r * 64, c * 128, 0, 16, 0.03125f, true, As, Bs);
}

// PV: 64-row tiles, steps r+1 (r=0..31); 1024 jobs in DESCENDING-length rank order
// (blockIdx = rank; round-robin dispatch stratifies long jobs across XCDs/CUs = LPT).
__global__ __launch_bounds__(256, 2)
void gemm_pv(const unsigned short* __restrict__ P, const unsigned short* __restrict__ Vt,
             float* __restrict__ out)
{
    const int S = 2048, D = 1024;
    const long long SS = (long long)S * S, DS = (long long)D * S, SD = (long long)S * D;
    __shared__ unsigned short As[2 * 4096];
    __shared__ unsigned short Bs[2 * 8192];
    const int rank = blockIdx.x;                         // 0..1023, longest first
    const int r = 31 - (rank >> 5);                      // 32 jobs per length class
    const int u = rank & 31;
    const int b = u >> 3, c = u & 7;
    // P zero-padded to 64-boundary per row covers reads k < (r+1)*64
    core_tile<2, float>(P + b * SS, Vt + b * DS, out + b * SD, S, S, D,
        r * 64, c * 128, 0, r + 1, 1.0f, true, As, Bs);
}

// ---- causal row softmax: bf16 scores in, bf16 P out ----
__device__ __forceinline__ float waveMax(float v) {
#pragma unroll
    for (int o = 32; o > 0; o >>= 1) v = fmaxf(v, __shfl_xor(v, o, 64));
    return v;
}
__device__ __forceinline__ float waveSum(float v) {
#pragma unroll
    for (int o = 32; o > 0; o >>= 1) v += __shfl_xor(v, o, 64);
    return v;
}

__global__ __launch_bounds__(256)
void softmax_causal(const unsigned short* __restrict__ S, unsigned short* __restrict__ P,
                    int Slen) {
    __shared__ float e[2048];
    __shared__ float red[4];
    long long row = blockIdx.x;
    int q = (int)(row % Slen);
    const unsigned short* srow = S + row * (long long)Slen;
    unsigned short* prow = P + row * (long long)Slen;
    int len = q + 1;
    int t = threadIdx.x;

    int n8 = len >> 3;
    float mx = -3.0e38f;
    for (int i = t; i < n8; i += 256) {
        uint4 v = reinterpret_cast<const uint4*>(srow)[i];
        float f0 = __uint_as_float(v.x << 16), f1 = __uint_as_float(v.x & 0xffff0000u);
        float f2 = __uint_as_float(v.y << 16), f3 = __uint_as_float(v.y & 0xffff0000u);
        float f4 = __uint_as_float(v.z << 16), f5 = __uint_as_float(v.z & 0xffff0000u);
        float f6 = __uint_as_float(v.w << 16), f7 = __uint_as_float(v.w & 0xffff0000u);
        e[8 * i + 0] = f0; e[8 * i + 1] = f1; e[8 * i + 2] = f2; e[8 * i + 3] = f3;
        e[8 * i + 4] = f4; e[8 * i + 5] = f5; e[8 * i + 6] = f6; e[8 * i + 7] = f7;
        mx = fmaxf(mx, fmaxf(fmaxf(fmaxf(f0, f1), fmaxf(f2, f3)),
                             fmaxf(fmaxf(f4, f5), fmaxf(f6, f7))));
    }
    if (t < (len & 7)) {
        float v = bf2f(srow[n8 * 8 + t]);
        e[n8 * 8 + t] = v;
        mx = fmaxf(mx, v);
    }
    mx = waveMax(mx);
    if ((t & 63) == 0) red[t >> 6] = mx;
    __syncthreads();
    mx = fmaxf(fmaxf(red[0], red[1]), fmaxf(red[2], red[3]));

    float sum = 0.f;
    for (int k = t; k < len; k += 256) {
        float v = __expf(e[k] - mx);
        e[k] = v;
        sum += v;
    }
    sum = waveSum(sum);
    __syncthreads();
    if ((t & 63) == 0) red[t >> 6] = sum;
    __syncthreads();
    sum = red[0] + red[1] + red[2] + red[3];
    float inv = 1.0f / sum;

    int wlim = ((q >> 6) + 1) << 6;   // PV 64-row tiles read only k < roundup(len,64)
    __syncthreads();
    for (int i = t; i < (wlim >> 2); i += 256) {
        int k = 4 * i;
        ushort4 o;
        o.x = (k + 0 < len) ? f2bf(e[k + 0] * inv) : (unsigned short)0;
        o.y = (k + 1 < len) ? f2bf(e[k + 1] * inv) : (unsigned short)0;
        o.z = (k + 2 < len) ? f2bf(e[k + 2] * inv) : (unsigned short)0;
        o.w = (k + 3 < len) ? f2bf(e[k + 3] * inv) : (unsigned short)0;
        reinterpret_cast<ushort4*>(prow)[i] = o;
    }
}

extern "C" void kernel_launch(void* const* d_in, const int* in_sizes, int n_in,
                              void* d_out, int out_size, void* d_ws, size_t ws_size,
                              hipStream_t stream) {
    const int B = 4, S = 2048, D = 1024;
    const float* X  = (const float*)d_in[0];
    const float* Wq = (const float*)d_in[1];
    const float* Wk = (const float*)d_in[2];
    const float* Wv = (const float*)d_in[3];
    float* out = (float*)d_out;

    char* ws = (char*)d_ws;
    unsigned short* Xb    = (unsigned short*)ws; ws += (size_t)B * S * D * 2;
    unsigned short* WqT   = (unsigned short*)ws; ws += (size_t)D * D * 2;
    unsigned short* WkT   = (unsigned short*)ws; ws += (size_t)D * D * 2;
    unsigned short* Wvb   = (unsigned short*)ws; ws += (size_t)D * D * 2;
    unsigned short* MTb   = (unsigned short*)ws; ws += (size_t)D * D * 2;
    unsigned short* XMb   = (unsigned short*)ws; ws += (size_t)B * S * D * 2;
    unsigned short* Vt    = (unsigned short*)ws; ws += (size_t)B * D * S * 2;
    unsigned short* Sc    = (unsigned short*)ws; ws += (size_t)B * S * S * 2;
    unsigned short* P     = (unsigned short*)ws; ws += (size_t)B * S * S * 2;
    float*          Mpart = (float*)ws;          ws += (size_t)4 * D * D * 4;

    // 1) converts + W transposes
    convt_k<<<dim3(16, 32, 7), 256, 0, stream>>>(X, Wq, Wk, Wv, Xb, WqT, WkT, Wvb);

    dim3 blk(256);
    // 2) MT = Wk^T * Wq, split-K (z = k-chunk of 256)
    gemm0<float><<<dim3(8, 8, 4), blk, 0, stream>>>(
        WkT, WqT, Mpart, D, D, D, 256, 256, 256, (long long)D * D, 1.0f);
    reduce4_k<<<1024, 256, 0, stream>>>(Mpart, MTb, D * D / 4);

    // 3) XM = Xb*M  +  Vt = Wv @ X^T : 1024 uniform 16-step jobs
    gemm_xmvt<<<dim3(1024, 1, 1), blk, 0, stream>>>(Xb, MTb, XMb, Wvb, Vt);

    // 4) scores (tri, /32, bf16): 1088 uniform 16-step 64-row jobs (4.25/CU)
    gemm_sc<<<dim3(1088, 1, 1), blk, 0, stream>>>(XMb, Xb, Sc);

    // 5) causal softmax -> P
    softmax_causal<<<B * S, 256, 0, stream>>>(Sc, P, S);

    // 6) out = P @ Vt^T : 1024 64-row jobs, descending-length LPT order, direct f32
    gemm_pv<<<dim3(1024, 1, 1), blk, 0, stream>>>(P, Vt, out);
}